// Round 1
// baseline (43.813 us; speedup 1.0000x reference)
//
#include <hip/hip_runtime.h>
#include <math.h>

#define B 1000
#define D 8
#define PRE 98
#define NEXT 512
#define SC 32
#define ANT 5
#define BM 16
#define NT ((B + BM - 1) / BM)  // 63 tiles of 16 rows

// ---------------------------------------------------------------------------
// Kernel 0: coef[d][c] = b_mat[d][c] * sum_a h_mat[d][k_idx[c]][a] * a_mat[c][a]
// ---------------------------------------------------------------------------
__global__ __launch_bounds__(256) void k_coef(const float* __restrict__ b_mat,
                                              const float* __restrict__ h_mat,
                                              const float* __restrict__ a_mat,
                                              const int* __restrict__ k_idx,
                                              float* __restrict__ coef) {
    int t = threadIdx.x;          // exactly 256 = D*SC
    int d = t >> 5, c = t & 31;
    int kk = k_idx[c];
    float s = 0.f;
#pragma unroll
    for (int a = 0; a < ANT; ++a)
        s += h_mat[(d * SC + kk) * ANT + a] * a_mat[c * ANT + a];
    coef[t] = b_mat[d * SC + c] * s;
}

// ---------------------------------------------------------------------------
// Kernel 1: per (d, 16-row tile): GEMM1 + bias + relu + LayerNorm + GEMM2
//           + bias + relu, scaled by coef -> part[d][b][c]
// ---------------------------------------------------------------------------
__global__ __launch_bounds__(256) void k_main(const float* __restrict__ x,
                                              const float* __restrict__ sub_w,
                                              const float* __restrict__ sub_b,
                                              const float* __restrict__ gamma,
                                              const float* __restrict__ beta,
                                              const float* __restrict__ cut_w,
                                              const float* __restrict__ cut_b,
                                              const float* __restrict__ coef,
                                              float* __restrict__ part) {
    __shared__ float x_lds[BM][PRE];
    __shared__ float h_lds[BM][NEXT];
    __shared__ float mu_s[BM], rs_s[BM];

    int t = threadIdx.x;
    int d = blockIdx.x / NT;
    int tile = blockIdx.x - d * NT;
    int b0 = tile * BM;

    // ---- stage x tile into LDS (zero-fill rows past B) ----
    for (int idx = t; idx < BM * PRE; idx += 256) {
        int r = idx / PRE, i = idx - r * PRE;
        int b = b0 + r;
        x_lds[r][i] = (b < B) ? x[b * (D * PRE) + d * PRE + i] : 0.f;
    }
    __syncthreads();

    // ---- GEMM1: h = relu(x_tile @ sub_w[d] + sub_b[d]) ----
    // thread -> 8 rows x 4 consecutive columns
    int cl = t & 127;   // column quad index: columns cl*4 .. cl*4+3
    int r0 = (t >> 7) * 8;  // rows r0 .. r0+7
    float acc[8][4];
#pragma unroll
    for (int r = 0; r < 8; ++r)
#pragma unroll
        for (int i = 0; i < 4; ++i) acc[r][i] = 0.f;

    const float* sw = sub_w + d * PRE * NEXT;
    for (int k = 0; k < PRE; ++k) {
        float4 w = *reinterpret_cast<const float4*>(sw + k * NEXT + cl * 4);
#pragma unroll
        for (int r = 0; r < 8; ++r) {
            float xv = x_lds[r0 + r][k];
            acc[r][0] = fmaf(xv, w.x, acc[r][0]);
            acc[r][1] = fmaf(xv, w.y, acc[r][1]);
            acc[r][2] = fmaf(xv, w.z, acc[r][2]);
            acc[r][3] = fmaf(xv, w.w, acc[r][3]);
        }
    }
    float4 bb = *reinterpret_cast<const float4*>(sub_b + d * NEXT + cl * 4);
#pragma unroll
    for (int r = 0; r < 8; ++r) {
        float4 hv;
        hv.x = fmaxf(acc[r][0] + bb.x, 0.f);
        hv.y = fmaxf(acc[r][1] + bb.y, 0.f);
        hv.z = fmaxf(acc[r][2] + bb.z, 0.f);
        hv.w = fmaxf(acc[r][3] + bb.w, 0.f);
        *reinterpret_cast<float4*>(&h_lds[r0 + r][cl * 4]) = hv;
    }
    __syncthreads();

    // ---- LayerNorm stats: 16 threads per row, shuffle reduce ----
    {
        int row = t >> 4, l16 = t & 15;
        float s1 = 0.f, s2 = 0.f;
        for (int o = l16; o < NEXT; o += 16) {
            float v = h_lds[row][o];
            s1 += v;
            s2 += v * v;
        }
#pragma unroll
        for (int off = 8; off >= 1; off >>= 1) {
            s1 += __shfl_xor(s1, off);
            s2 += __shfl_xor(s2, off);
        }
        if (l16 == 0) {
            float mu = s1 * (1.f / NEXT);
            float var = s2 * (1.f / NEXT) - mu * mu;
            mu_s[row] = mu;
            rs_s[row] = rsqrtf(var + 1e-5f);
        }
    }
    __syncthreads();

    // ---- normalize in place (+ gamma/beta) ----
    {
        const float* g = gamma + d * NEXT;
        const float* bt = beta + d * NEXT;
        for (int idx = t; idx < BM * NEXT; idx += 256) {
            int r = idx >> 9, o = idx & (NEXT - 1);
            h_lds[r][o] = (h_lds[r][o] - mu_s[r]) * rs_s[r] * g[o] + bt[o];
        }
    }
    __syncthreads();

    // ---- GEMM2: cut = relu(h @ cut_w[d] + cut_b[d]); part = cut * coef ----
    {
        int c = t & 31, rr = t >> 5;  // rows rr and rr+8
        float a0 = 0.f, a1 = 0.f;
        const float* cw = cut_w + d * NEXT * SC;
        for (int o = 0; o < NEXT; ++o) {
            float w = cw[o * SC + c];
            a0 = fmaf(h_lds[rr][o], w, a0);
            a1 = fmaf(h_lds[rr + 8][o], w, a1);
        }
        float cb = cut_b[d * SC + c];
        float cf = coef[d * SC + c];
        int b_a = b0 + rr, b_b = b0 + rr + 8;
        if (b_a < B) part[(d * B + b_a) * SC + c] = fmaxf(a0 + cb, 0.f) * cf;
        if (b_b < B) part[(d * B + b_b) * SC + c] = fmaxf(a1 + cb, 0.f) * cf;
    }
}

// ---------------------------------------------------------------------------
// Kernel 2: tail MLP. One wave per row b: z(32)->fc3(98)->fc4(49)->out(10)
//           -> log_softmax.  B = 1000 = 250 blocks * 4 waves exactly.
// ---------------------------------------------------------------------------
__global__ __launch_bounds__(256) void k_tail(const float* __restrict__ part,
                                              const float* __restrict__ noise,
                                              const float* __restrict__ a_mat,
                                              const float* __restrict__ clb,
                                              const float* __restrict__ fc3_w,
                                              const float* __restrict__ fc3_b,
                                              const float* __restrict__ fc4_w,
                                              const float* __restrict__ fc4_b,
                                              const float* __restrict__ out_w,
                                              const float* __restrict__ out_b,
                                              float* __restrict__ out) {
    __shared__ float w3[SC * 98];
    __shared__ float w4[98 * 49];
    __shared__ float wo[49 * 10];
    __shared__ float b3[98], b4[49], bo[10];
    __shared__ float z_s[4][SC];
    __shared__ float z3_s[4][98];
    __shared__ float z4_s[4][49];

    int t = threadIdx.x;
    for (int i = t; i < SC * 98; i += 256) w3[i] = fc3_w[i];
    for (int i = t; i < 98 * 49; i += 256) w4[i] = fc4_w[i];
    for (int i = t; i < 49 * 10; i += 256) wo[i] = out_w[i];
    if (t < 98) b3[t] = fc3_b[t];
    if (t < 49) b4[t] = fc4_b[t];
    if (t < 10) bo[t] = out_b[t];
    __syncthreads();

    int w = t >> 6, lane = t & 63;
    int b = blockIdx.x * 4 + w;

    // z = relu(sum_d part + noise . a_mat + cut_layer_bias)
    if (lane < SC) {
        int j = lane;
        float s = clb[j];
#pragma unroll
        for (int d = 0; d < D; ++d) s += part[(d * B + b) * SC + j];
#pragma unroll
        for (int a = 0; a < ANT; ++a)
            s = fmaf(noise[(b * SC + j) * ANT + a], a_mat[j * ANT + a], s);
        z_s[w][j] = fmaxf(s, 0.f);
    }
    __syncthreads();

    // fc3: 98 outputs
    for (int o = lane; o < 98; o += 64) {
        float s = b3[o];
#pragma unroll
        for (int j = 0; j < SC; ++j) s = fmaf(z_s[w][j], w3[j * 98 + o], s);
        z3_s[w][o] = fmaxf(s, 0.f);
    }
    __syncthreads();

    // fc4: 49 outputs
    if (lane < 49) {
        float s = b4[lane];
        for (int j = 0; j < 98; ++j) s = fmaf(z3_s[w][j], w4[j * 49 + lane], s);
        z4_s[w][lane] = fmaxf(s, 0.f);
    }
    __syncthreads();

    // out: 10 logits + log_softmax across lanes 0..9 (16-lane shuffle group)
    float v = -INFINITY;
    if (lane < 10) {
        float s = bo[lane];
        for (int j = 0; j < 49; ++j) s = fmaf(z4_s[w][j], wo[j * 10 + lane], s);
        v = s;
    }
    float m = v;
#pragma unroll
    for (int off = 8; off >= 1; off >>= 1) m = fmaxf(m, __shfl_xor(m, off, 16));
    float e = (lane < 10) ? expf(v - m) : 0.f;
    float ssum = e;
#pragma unroll
    for (int off = 8; off >= 1; off >>= 1) ssum += __shfl_xor(ssum, off, 16);
    if (lane < 10) out[b * 10 + lane] = v - m - logf(ssum);
}

// ---------------------------------------------------------------------------
extern "C" void kernel_launch(void* const* d_in, const int* in_sizes, int n_in,
                              void* d_out, int out_size, void* d_ws, size_t ws_size,
                              hipStream_t stream) {
    const float* x      = (const float*)d_in[0];
    const float* noise  = (const float*)d_in[1];
    const float* sub_w  = (const float*)d_in[2];
    const float* sub_b  = (const float*)d_in[3];
    const float* ln_g   = (const float*)d_in[4];
    const float* ln_b   = (const float*)d_in[5];
    const float* cut_w  = (const float*)d_in[6];
    const float* cut_b  = (const float*)d_in[7];
    const float* b_mat  = (const float*)d_in[8];
    const float* h_mat  = (const float*)d_in[9];
    const float* a_mat  = (const float*)d_in[10];
    const float* clb    = (const float*)d_in[11];
    const float* fc3_w  = (const float*)d_in[12];
    const float* fc3_b  = (const float*)d_in[13];
    const float* fc4_w  = (const float*)d_in[14];
    const float* fc4_b  = (const float*)d_in[15];
    const float* out_w  = (const float*)d_in[16];
    const float* out_b  = (const float*)d_in[17];
    const int*   k_idx  = (const int*)d_in[18];
    float* out = (float*)d_out;

    float* coef = (float*)d_ws;        // 256 floats
    float* part = coef + 256;          // D*B*SC floats = 256000 (1 MB)

    k_coef<<<1, 256, 0, stream>>>(b_mat, h_mat, a_mat, k_idx, coef);
    k_main<<<D * NT, 256, 0, stream>>>(x, sub_w, sub_b, ln_g, ln_b, cut_w,
                                       cut_b, coef, part);
    k_tail<<<B / 4, 256, 0, stream>>>(part, noise, a_mat, clb, fc3_w, fc3_b,
                                      fc4_w, fc4_b, out_w, out_b, out);
}